// Round 1
// baseline (586.861 us; speedup 1.0000x reference)
//
#include <hip/hip_runtime.h>
#include <hip/hip_bf16.h>

typedef __attribute__((ext_vector_type(8))) short short8;
typedef __attribute__((ext_vector_type(4))) float f32x4;

__device__ __forceinline__ unsigned short f2bf(float x) {
    unsigned int u = __float_as_uint(x);
    u = (u + 0x7fffu + ((u >> 16) & 1u)) >> 16;   // RNE
    return (unsigned short)u;
}

// ---------------------------------------------------------------------------
// s[cv][b][c] = 1 + PixelNorm(EqualLinear(latent))
// grid 16 (cv*8+b), block 256 (c)
__global__ void style_kernel(const float* __restrict__ latent,
                             const float* __restrict__ elw0, const float* __restrict__ elb0,
                             const float* __restrict__ elw1, const float* __restrict__ elb1,
                             float* __restrict__ s_arr) {
    const int cv = blockIdx.x >> 3;
    const int b  = blockIdx.x & 7;
    const int c  = threadIdx.x;
    const float* elw = cv ? elw1 : elw0;
    const float* elb = cv ? elb1 : elb0;

    __shared__ float lat[512];
    lat[c] = latent[b * 512 + c];
    lat[c + 256] = latent[b * 512 + c + 256];
    __syncthreads();

    float accv = 0.f;
    const float* wrow = elw + (size_t)c * 512;
#pragma unroll 8
    for (int k = 0; k < 512; ++k) accv += lat[k] * wrow[k];
    const float lin = accv * 0.04419417382415922f + elb[c];   // 1/sqrt(512)

    float sq = lin * lin;
#pragma unroll
    for (int off = 32; off >= 1; off >>= 1) sq += __shfl_xor(sq, off);
    __shared__ float wsum[4];
    if ((threadIdx.x & 63) == 0) wsum[threadIdx.x >> 6] = sq;
    __syncthreads();
    const float total = wsum[0] + wsum[1] + wsum[2] + wsum[3];
    const float s = 1.0f + lin * rsqrtf(total * (1.0f / 256.0f) + 1e-8f);
    s_arr[(cv * 8 + b) * 256 + c] = s;
}

// wsq[cv][o][c] = sum_t (w*sc)^2 ; grid 512 (cv*256+o), block 256 (c)
__global__ void wsq_kernel(const float* __restrict__ w0, const float* __restrict__ w1,
                           float* __restrict__ wsq) {
    const int cv = blockIdx.x >> 8;
    const int o  = blockIdx.x & 255;
    const int c  = threadIdx.x;
    const float* w = cv ? w1 : w0;
    const size_t base = ((size_t)o * 256 + c) * 9;
    float ssum = 0.f;
#pragma unroll
    for (int t = 0; t < 9; ++t) { float v = w[base + t]; ssum += v * v; }
    wsq[((size_t)cv * 256 + o) * 256 + c] = ssum * (2.0f / 2304.0f);
}

// d[cv][b][o] = rsqrt(sum_c s^2 * wsq + 1e-5) ; grid 16 (cv*8+b), block 256 (o)
__global__ void demod_kernel(const float* __restrict__ s_arr, const float* __restrict__ wsq,
                             float* __restrict__ d_arr) {
    const int cv = blockIdx.x >> 3;
    const int b  = blockIdx.x & 7;
    const int o  = threadIdx.x;
    __shared__ float ss[256];
    float sv = s_arr[(cv * 8 + b) * 256 + o];
    ss[o] = sv * sv;
    __syncthreads();
    const float* wrow = wsq + ((size_t)cv * 256 + o) * 256;
    float accv = 0.f;
#pragma unroll 8
    for (int c = 0; c < 256; ++c) accv += ss[c] * wrow[c];
    d_arr[(cv * 8 + b) * 256 + o] = rsqrtf(accv + 1e-5f);
}

// wmod[cv][b][t][cc][o][c'] (bf16) = w[o][c][t]*sc*s[b,c]*d[b,o]
// grid (18432, 2), block 256
__global__ void fold_kernel(const float* __restrict__ w0, const float* __restrict__ w1,
                            const float* __restrict__ s_arr, const float* __restrict__ d_arr,
                            unsigned short* __restrict__ wm0, unsigned short* __restrict__ wm1) {
    const int cv = blockIdx.y;
    const int e  = blockIdx.x * 256 + threadIdx.x;
    const float* w = cv ? w1 : w0;
    unsigned short* wm = cv ? wm1 : wm0;
    const int low = e & 65535;
    const int g   = e >> 16;              // 0..71
    const int b   = g / 9;
    const int t   = g - b * 9;
    const int cp  = low & 31;
    const int o   = (low >> 5) & 255;
    const int cc  = low >> 13;
    const int c   = cc * 32 + cp;
    const float val = w[((size_t)o * 256 + c) * 9 + t] * 0.029462782549439483f  // sqrt(2/2304)
                    * s_arr[(cv * 8 + b) * 256 + c] * d_arr[(cv * 8 + b) * 256 + o];
    wm[e] = f2bf(val);
}

// ---------------------------------------------------------------------------
// Modulated conv as implicit GEMM: M=256 (all o), N=64 (half row), K=2304.
// Fused: +bias, leaky_relu*sqrt(2), PixelNorm over channels.
// grid 2048 (b*256 + h*2 + wtile), block 256 (4 waves, each 64x64).
template<bool IN_BF16, bool OUT_BF16>
__global__ __launch_bounds__(256, 2) void conv_kernel(
    const void* __restrict__ in_v, const unsigned short* __restrict__ wmod,
    const float* __restrict__ bias, void* __restrict__ out_v) {
    const float*          inF  = (const float*)in_v;
    const unsigned short* inB  = (const unsigned short*)in_v;
    float*                outF = (float*)out_v;
    unsigned short*       outB = (unsigned short*)out_v;

    __shared__ __align__(16) char lds[25600];   // A: 256 rows x 80B, B: 64 rows x 80B
    __shared__ float sbias[256];

    const int tid  = threadIdx.x;
    const int bx   = blockIdx.x;
    const int b    = bx >> 8;
    const int h    = (bx >> 1) & 127;
    const int w0   = (bx & 1) << 6;
    const int lane = tid & 63;
    const int wr   = tid >> 6;      // wave id = M-quarter
    const int l15  = lane & 15;
    const int lq   = lane >> 4;

    sbias[tid] = bias[tid];

    int aoff[4], boff[4];
#pragma unroll
    for (int m = 0; m < 4; ++m)  aoff[m] = (wr * 64 + m * 16 + l15) * 80 + lq * 16;
#pragma unroll
    for (int nf = 0; nf < 4; ++nf) boff[nf] = 20480 + (nf * 16 + l15) * 80 + lq * 16;

    const int bn  = tid & 63;       // pixel within tile
    const int bc8 = tid >> 6;       // c-octet within BK
    const size_t inbase = (size_t)b * (256 * 16384);
    const unsigned short* wmb = wmod + (size_t)b * 589824;

    f32x4 acc[4][4];
#pragma unroll
    for (int m = 0; m < 4; ++m)
#pragma unroll
        for (int nf = 0; nf < 4; ++nf) acc[m][nf] = (f32x4){0.f, 0.f, 0.f, 0.f};

    int4 av0, av1, av2, av3, bv;

    auto load_stage = [&](int kk) {
        const int t  = kk >> 3;
        const int cc = kk & 7;
        const int dy = t / 3;
        const int dx = t - dy * 3;
        const int row = h + dy - 1;
        const int col = w0 + bn + dx - 1;
        const bool ok = ((unsigned)row < 128u) && ((unsigned)col < 128u);
        const int4* ap = (const int4*)(wmb + (size_t)kk * 8192);
        av0 = ap[tid];
        av1 = ap[tid + 256];
        av2 = ap[tid + 512];
        av3 = ap[tid + 768];
        const int cbase = cc * 32 + bc8 * 8;
        const long pix = (long)row * 128 + col;
        unsigned short u[8];
#pragma unroll
        for (int j = 0; j < 8; ++j) {
            const long idx = (long)inbase + (long)(cbase + j) * 16384 + pix;
            if (IN_BF16) {
                u[j] = ok ? inB[idx] : (unsigned short)0;
            } else {
                const float v = ok ? inF[idx] : 0.f;
                u[j] = f2bf(v);
            }
        }
        int4 p;
        p.x = (int)((unsigned)u[0] | ((unsigned)u[1] << 16));
        p.y = (int)((unsigned)u[2] | ((unsigned)u[3] << 16));
        p.z = (int)((unsigned)u[4] | ((unsigned)u[5] << 16));
        p.w = (int)((unsigned)u[6] | ((unsigned)u[7] << 16));
        bv = p;
    };

    auto write_stage = [&]() {
        const int q16 = (tid & 3) * 16;
        *(int4*)(lds + ((tid) >> 2) * 80 + q16)        = av0;
        *(int4*)(lds + ((tid + 256) >> 2) * 80 + q16)  = av1;
        *(int4*)(lds + ((tid + 512) >> 2) * 80 + q16)  = av2;
        *(int4*)(lds + ((tid + 768) >> 2) * 80 + q16)  = av3;
        *(int4*)(lds + 20480 + bn * 80 + bc8 * 16)     = bv;
    };

    load_stage(0);
    write_stage();
    __syncthreads();

#pragma unroll 1
    for (int kk = 0; kk < 71; ++kk) {
        load_stage(kk + 1);            // global loads for next step (in-flight)
        short8 af[4], bfr[4];
#pragma unroll
        for (int m = 0; m < 4; ++m)  af[m]  = *(const short8*)(lds + aoff[m]);
#pragma unroll
        for (int nf = 0; nf < 4; ++nf) bfr[nf] = *(const short8*)(lds + boff[nf]);
#pragma unroll
        for (int m = 0; m < 4; ++m)
#pragma unroll
            for (int nf = 0; nf < 4; ++nf)
                acc[m][nf] = __builtin_amdgcn_mfma_f32_16x16x32_bf16(af[m], bfr[nf], acc[m][nf], 0, 0, 0);
        __syncthreads();
        write_stage();                 // waits vmcnt internally (T14 split)
        __syncthreads();
    }
    {   // last K-step
        short8 af[4], bfr[4];
#pragma unroll
        for (int m = 0; m < 4; ++m)  af[m]  = *(const short8*)(lds + aoff[m]);
#pragma unroll
        for (int nf = 0; nf < 4; ++nf) bfr[nf] = *(const short8*)(lds + boff[nf]);
#pragma unroll
        for (int m = 0; m < 4; ++m)
#pragma unroll
            for (int nf = 0; nf < 4; ++nf)
                acc[m][nf] = __builtin_amdgcn_mfma_f32_16x16x32_bf16(af[m], bfr[nf], acc[m][nf], 0, 0, 0);
    }
    __syncthreads();   // all frag reads done; LDS reused for pixelnorm reduce

    // epilogue: bias + leaky*sqrt2, per-pixel channel sum of squares
    float psum[4] = {0.f, 0.f, 0.f, 0.f};
    const float actGain = 1.4142135623730951f;
#pragma unroll
    for (int m = 0; m < 4; ++m) {
#pragma unroll
        for (int r = 0; r < 4; ++r) {
            const int o = wr * 64 + m * 16 + lq * 4 + r;
            const float bo = sbias[o];
#pragma unroll
            for (int nf = 0; nf < 4; ++nf) {
                float v = acc[m][nf][r] + bo;
                v = (v > 0.f ? v : 0.2f * v) * actGain;
                acc[m][nf][r] = v;
                psum[nf] += v * v;
            }
        }
    }
#pragma unroll
    for (int nf = 0; nf < 4; ++nf) {
        psum[nf] += __shfl_xor(psum[nf], 16);
        psum[nf] += __shfl_xor(psum[nf], 32);
    }
    float* red = (float*)lds;     // [4 waves][64 pixels]
    if (lane < 16) {
#pragma unroll
        for (int nf = 0; nf < 4; ++nf) red[wr * 64 + nf * 16 + lane] = psum[nf];
    }
    __syncthreads();
    float rs[4];
#pragma unroll
    for (int nf = 0; nf < 4; ++nf) {
        const int n = nf * 16 + l15;
        const float ssum = red[n] + red[64 + n] + red[128 + n] + red[192 + n];
        rs[nf] = rsqrtf(ssum * (1.0f / 256.0f) + 1e-8f);
    }
#pragma unroll
    for (int m = 0; m < 4; ++m) {
#pragma unroll
        for (int r = 0; r < 4; ++r) {
            const int o = wr * 64 + m * 16 + lq * 4 + r;
            const size_t base = (size_t)((b * 256 + o) * 128 + h) * 128 + w0;
#pragma unroll
            for (int nf = 0; nf < 4; ++nf) {
                const int n = nf * 16 + l15;
                const float v = acc[m][nf][r] * rs[nf];
                if (OUT_BF16) outB[base + n] = f2bf(v);
                else          outF[base + n] = v;
            }
        }
    }
}

// ---------------------------------------------------------------------------
extern "C" void kernel_launch(void* const* d_in, const int* in_sizes, int n_in,
                              void* d_out, int out_size, void* d_ws, size_t ws_size,
                              hipStream_t stream) {
    (void)in_sizes; (void)n_in; (void)out_size; (void)ws_size;
    const float* x      = (const float*)d_in[0];
    const float* latent = (const float*)d_in[1];
    const float* w0     = (const float*)d_in[2];
    const float* b0     = (const float*)d_in[3];
    const float* el0w   = (const float*)d_in[4];
    const float* el0b   = (const float*)d_in[5];
    const float* w1     = (const float*)d_in[6];
    const float* b1     = (const float*)d_in[7];
    const float* el1w   = (const float*)d_in[8];
    const float* el1b   = (const float*)d_in[9];

    char* ws = (char*)d_ws;
    float* s_arr = (float*)ws;                               // 2*8*256 f32
    float* d_arr = (float*)(ws + 16384);                     // 2*8*256 f32
    float* wsq   = (float*)(ws + 32768);                     // 2*256*256 f32
    unsigned short* wm0 = (unsigned short*)(ws + 557056);                 // 8*9*8*256*32 bf16
    unsigned short* wm1 = (unsigned short*)(ws + 557056 + 9437184);
    unsigned short* tmp = (unsigned short*)(ws + 557056 + 2 * 9437184);   // 8*256*128*128 bf16

    style_kernel<<<16, 256, 0, stream>>>(latent, el0w, el0b, el1w, el1b, s_arr);
    wsq_kernel<<<512, 256, 0, stream>>>(w0, w1, wsq);
    demod_kernel<<<16, 256, 0, stream>>>(s_arr, wsq, d_arr);
    fold_kernel<<<dim3(18432, 2), 256, 0, stream>>>(w0, w1, s_arr, d_arr, wm0, wm1);
    conv_kernel<false, true><<<2048, 256, 0, stream>>>(x, wm0, b0, tmp);
    conv_kernel<true, false><<<2048, 256, 0, stream>>>(tmp, wm1, b1, d_out);
}